// Round 1
// baseline (85.408 us; speedup 1.0000x reference)
//
#include <hip/hip_runtime.h>
#include <math.h>

// Problem constants (B=64, K=32, L=8192 from reference setup_inputs).
constexpr int Lc = 8192;
constexpr int Kc = 32;
constexpr int Bc = 64;

// cot(pi*d/L) for 1 <= d <= L-1, computed with reflection to avoid
// catastrophic cancellation near d ~ L (angle near pi).
__device__ inline float cot_pi_frac(int d) {
    int dd = d;
    float s = 1.0f;
    if (dd > Lc / 2) { dd = Lc - dd; s = -1.0f; }
    float ang = (float)((double)M_PI * (double)dd / (double)Lc);
    return s * (cosf(ang) / sinf(ang));
}

// K1: w[n] = sum_k lam[k] * ev[k][n]; also zero-init the Bacc accumulator.
__global__ __launch_bounds__(256) void k_w(const float* __restrict__ ev,
                                           const float* __restrict__ lam,
                                           float* __restrict__ wsw,
                                           float* __restrict__ Bacc) {
    int n = blockIdx.x * 256 + threadIdx.x;
    float acc = 0.0f;
#pragma unroll
    for (int k = 0; k < Kc; ++k)
        acc = fmaf(lam[k], ev[k * Lc + n], acc);
    wsw[n] = acc;
    Bacc[n] = 0.0f;
}

// K2: per-batch complex scalar s_b = sum_i rfft(u_b)[i], via closed form:
//   sigma_r = sum_{even n} u[n] + 4096*u[0]
//   sigma_i = -sum_{odd n} u[n] * cot(pi*n/L)
__global__ __launch_bounds__(256) void k_sigma(const float* __restrict__ u,
                                               float* __restrict__ sr,
                                               float* __restrict__ si) {
    int b = blockIdx.x;
    int t = threadIdx.x;
    const float* ub = u + b * Lc;
    double dar = 0.0, dai = 0.0;
    for (int n = t; n < Lc; n += 256) {
        float v = ub[n];
        if (n & 1) {
            dai -= (double)v * (double)cot_pi_frac(n);
        } else {
            dar += (double)v;
            if (n == 0) dar += 4096.0 * (double)v;
        }
    }
    // wave (64-lane) reduction, then cross-wave via LDS
    for (int off = 32; off > 0; off >>= 1) {
        dar += __shfl_down(dar, off);
        dai += __shfl_down(dai, off);
    }
    __shared__ double lsr[4], lsi[4];
    int wave = t >> 6, lane = t & 63;
    if (lane == 0) { lsr[wave] = dar; lsi[wave] = dai; }
    __syncthreads();
    if (t == 0) {
        sr[b] = (float)(lsr[0] + lsr[1] + lsr[2] + lsr[3]);
        si[b] = (float)(lsi[0] + lsi[1] + lsi[2] + lsi[3]);
    }
}

// K3: B[n] = -(2/L) * sum_{odd d} cot(pi*d/L) * w[(n-d) mod L]
// Grid = 32 n-chunks x 8 d-slices = 256 blocks. w segment + cot slice in LDS.
__global__ __launch_bounds__(256) void k_conv(const float* __restrict__ wsw,
                                              float* __restrict__ Bacc) {
    __shared__ float s_w[1280];
    __shared__ float s_c[512];
    int t = threadIdx.x;
    int cn = blockIdx.x & 31;   // n-chunk
    int cd = blockIdx.x >> 5;   // d-slice
    int n0 = cn * 256;
    int dbase = cd * 1024;      // d = dbase + 2*i + 1, i in [0, 512)
    int base = n0 - dbase - 1023;  // s_w[j] = w[(base + j) & (L-1)]
    for (int j = t; j < 1280; j += 256)
        s_w[j] = wsw[(base + j) & (Lc - 1)];
    for (int i = t; i < 512; i += 256)
        s_c[i] = cot_pi_frac(dbase + 2 * i + 1);
    __syncthreads();
    float acc = 0.0f;
#pragma unroll 8
    for (int i = 0; i < 512; ++i)
        acc = fmaf(s_c[i], s_w[t + 1022 - 2 * i], acc);
    atomicAdd(&Bacc[n0 + t], acc * (-2.0f / (float)Lc));
}

// K4: out[b][n] = sr[b]*w[n] + si[b]*B[n]
__global__ __launch_bounds__(256) void k_out(const float* __restrict__ wsw,
                                             const float* __restrict__ sr,
                                             const float* __restrict__ si,
                                             const float* __restrict__ Bacc,
                                             float* __restrict__ out) {
    int idx = blockIdx.x * 256 + threadIdx.x;
    int b = idx >> 13;          // / 8192
    int n = idx & (Lc - 1);
    out[idx] = fmaf(sr[b], wsw[n], si[b] * Bacc[n]);
}

extern "C" void kernel_launch(void* const* d_in, const int* in_sizes, int n_in,
                              void* d_out, int out_size, void* d_ws, size_t ws_size,
                              hipStream_t stream) {
    const float* u   = (const float*)d_in[0];  // (64, 8192)
    const float* ev  = (const float*)d_in[1];  // (32, 8192)
    const float* lam = (const float*)d_in[2];  // (32,)  (already **0.25)
    float* out = (float*)d_out;                // (64, 8192)

    float* ws   = (float*)d_ws;
    float* wsw  = ws;                 // [0, 8192)       : w
    float* sr   = ws + Lc;            // [8192, 8256)    : sigma_r
    float* si   = ws + Lc + 64;       // [8256, 8320)    : sigma_i
    float* Bacc = ws + Lc + 128;      // [8320, 16512)   : B accumulator

    hipLaunchKernelGGL(k_w,     dim3(Lc / 256), dim3(256), 0, stream, ev, lam, wsw, Bacc);
    hipLaunchKernelGGL(k_sigma, dim3(Bc),       dim3(256), 0, stream, u, sr, si);
    hipLaunchKernelGGL(k_conv,  dim3(256),      dim3(256), 0, stream, wsw, Bacc);
    hipLaunchKernelGGL(k_out,   dim3(Bc * Lc / 256), dim3(256), 0, stream, wsw, sr, si, Bacc, out);
}